// Round 1
// baseline (425.186 us; speedup 1.0000x reference)
//
#include <hip/hip_runtime.h>
#include <math.h>

#define D_ 10
#define N_ 500
#define MD 5
#define NL 16     // n per block
#define MB 64     // m per block
#define STR 268   // per-n LDS stride in floats (16B aligned, stride%32=12 -> <=2-way bank alias)

__device__ __forceinline__ float fexp2(float x){ float r; asm("v_exp_f32 %0, %1" : "=v"(r) : "v"(x)); return r; }
__device__ __forceinline__ float flog2(float x){ float r; asm("v_log_f32 %0, %1" : "=v"(r) : "v"(x)); return r; }
__device__ __forceinline__ float frcp (float x){ float r; asm("v_rcp_f32 %0, %1" : "=v"(r) : "v"(x)); return r; }

#define LOG2E 1.4426950408889634f
#define LN2   0.6931471805599453f

__device__ __forceinline__ float fast_tanh(float x){
  // tanh(x) = 1 - 2/(exp(2x)+1); saturates correctly via inf/0
  float e = fexp2(x * (2.0f*LOG2E));
  return 1.0f - 2.0f*frcp(e + 1.0f);
}
__device__ __forceinline__ float softplus10(float x){
  // (1/10) ln(1+exp(10x)); |10x|<~6 for this data so no overflow path needed
  float e = fexp2(x * (10.0f*LOG2E));
  return (0.1f*LN2) * flog2(1.0f + e);
}

// LDS layout per n (word offsets):
//   0   : W0[5]                (softplus10(w_first))
//   8   : Wm[(l*5+j)*8 + k]    l=0..3 rows j=0..4, k=0..4 (transposed, softplus10)
//   168 : Wl[5]                (softplus10(w_last))
//   176 : bs[l*8 + j]          l=0..4 (raw)
//   216 : b_last               (raw)
//   224 : ta[l*8 + j]          l=0..4 (tanh(a_all))
__global__ __launch_bounds__(1024) void tennet_main(
    const float* __restrict__ X, const float* __restrict__ w_first,
    const float* __restrict__ w_mid, const float* __restrict__ w_last,
    const float* __restrict__ bs, const float* __restrict__ b_last,
    const float* __restrict__ a_all, float* __restrict__ out0)
{
  __shared__ float sm[NL*STR];
  int bid = blockIdx.x;
  int nchunk = bid & 31;          // 32 n-chunks (16 n each, covers 512 >= 500)
  int mchunk = (bid >> 5) & 15;   // 16 m-chunks of 64
  int d = bid >> 9;               // 10 d values
  int n0 = nchunk * NL;
  int m0 = mchunk * MB;
  int t = threadIdx.x;

  // --- cooperative staging: transform weights once per block ---
  for (int task = t; task < NL*161; task += 1024) {
    int nn = task / 161;
    int w  = task - nn*161;
    int n = n0 + nn;
    int nsrc = (n < N_) ? n : (N_-1);   // clamp so LDS is always valid data
    float* dst = &sm[nn*STR];
    if (w < 5) {
      dst[w] = softplus10(w_first[(d*N_ + nsrc)*MD + w]);
    } else if (w < 105) {
      int i = w - 5; int l = i/25; int r = i - l*25; int j = r/5; int k = r - j*5;
      dst[8 + (l*5 + j)*8 + k] =
          softplus10(w_mid[(((l*D_ + d)*N_) + nsrc)*25 + k*5 + j]);
    } else if (w < 110) {
      int k = w - 105;
      dst[168 + k] = softplus10(w_last[(d*N_ + nsrc)*MD + k]);
    } else if (w < 135) {
      int i = w - 110; int l = i/5; int j = i - l*5;
      dst[176 + l*8 + j] = bs[((l*D_ + d)*N_ + nsrc)*MD + j];
    } else if (w == 135) {
      dst[216] = b_last[d*N_ + nsrc];
    } else {
      int i = w - 136; int l = i/5; int j = i - l*5;
      dst[224 + l*8 + j] = fast_tanh(a_all[((l*D_ + d)*N_ + nsrc)*MD + j]);
    }
  }
  __syncthreads();

  int nl = t & (NL-1);
  int ml = t >> 4;
  int n = n0 + nl;
  int m = m0 + ml;
  const float* s = &sm[nl*STR];

  float x = X[m*D_ + d];

  float phis[5], phid[5];
  // layer 0 (k-dim = 1)
  #pragma unroll
  for (int j = 0; j < 5; ++j) {
    float w0 = s[j];
    float pre = x*w0 + s[176 + j];
    float th = fast_tanh(pre);
    float ta = s[224 + j];
    float td = 1.0f - th*th;
    phid[j] = w0 * (1.0f + ta*td);
    phis[j] = pre + th*ta;
  }
  // mid layers l = 1..4
  #pragma unroll
  for (int l = 1; l <= 4; ++l) {
    float nphis[5], nphid[5];
    #pragma unroll
    for (int j = 0; j < 5; ++j) {
      const float* wr = &s[8 + ((l-1)*5 + j)*8];   // row j: W[k][j] for k=0..4
      float pre = s[176 + l*8 + j];
      float pd = 0.0f;
      #pragma unroll
      for (int k = 0; k < 5; ++k) {
        pre += phis[k]*wr[k];
        pd  += phid[k]*wr[k];
      }
      float th = fast_tanh(pre);
      float ta = s[224 + l*8 + j];
      float td = 1.0f - th*th;
      nphid[j] = pd * (1.0f + ta*td);
      nphis[j] = pre + th*ta;
    }
    #pragma unroll
    for (int j = 0; j < 5; ++j) { phis[j] = nphis[j]; phid[j] = nphid[j]; }
  }
  // last layer (output dim = 1) + sigmoid'
  float pre = s[216], pd = 0.0f;
  #pragma unroll
  for (int k = 0; k < 5; ++k) { pre += phis[k]*s[168+k]; pd += phid[k]*s[168+k]; }
  float sg = frcp(1.0f + fexp2(-pre*LOG2E));
  float res = pd * sg * (1.0f - sg);

  if (n < N_) out0[(m*D_ + d)*N_ + n] = res;
}

// fm[m] = min_n mean_d( -ln(phidot[m,d,n] + 1e-10) )
__global__ __launch_bounds__(512) void tennet_fm(
    const float* __restrict__ out0, float* __restrict__ fm)
{
  int m = blockIdx.x;
  int t = threadIdx.x;
  float val = INFINITY;
  if (t < N_) {
    float acc = 0.0f;
    #pragma unroll
    for (int d = 0; d < D_; ++d) {
      float v = out0[(m*D_ + d)*N_ + t];
      acc += flog2(v + 1e-10f);
    }
    val = -acc * (LN2 / (float)D_);
  }
  // min-reduce: wave (64) then cross-wave via LDS
  #pragma unroll
  for (int off = 32; off; off >>= 1) {
    float o = __shfl_down(val, off, 64);
    val = fminf(val, o);
  }
  __shared__ float red[8];
  int wid = t >> 6;
  if ((t & 63) == 0) red[wid] = val;
  __syncthreads();
  if (t == 0) {
    float v = red[0];
    #pragma unroll
    for (int w = 1; w < 8; ++w) v = fminf(v, red[w]);
    fm[m] = v;
  }
}

extern "C" void kernel_launch(void* const* d_in, const int* in_sizes, int n_in,
                              void* d_out, int out_size, void* d_ws, size_t ws_size,
                              hipStream_t stream) {
  const float* X       = (const float*)d_in[0];
  const float* w_first = (const float*)d_in[1];
  const float* w_mid   = (const float*)d_in[2];
  const float* w_last  = (const float*)d_in[3];
  const float* bs      = (const float*)d_in[4];
  const float* b_last  = (const float*)d_in[5];
  const float* a_all   = (const float*)d_in[6];
  float* out0 = (float*)d_out;
  float* fm   = out0 + 1024*D_*N_;

  tennet_main<<<10*16*32, 1024, 0, stream>>>(X, w_first, w_mid, w_last, bs, b_last, a_all, out0);
  tennet_fm<<<1024, 512, 0, stream>>>(out0, fm);
}

// Round 2
// 90.806 us; speedup vs baseline: 4.6824x; 4.6824x over previous
//
#include <hip/hip_runtime.h>
#include <math.h>

#define D_ 10
#define N_ 500
#define REC 164   // packed per-(d,n) weight record, floats

__device__ __forceinline__ float fexp2(float x){ float r; asm("v_exp_f32 %0, %1" : "=v"(r) : "v"(x)); return r; }
__device__ __forceinline__ float flog2(float x){ float r; asm("v_log_f32 %0, %1" : "=v"(r) : "v"(x)); return r; }
__device__ __forceinline__ float frcp (float x){ float r; asm("v_rcp_f32 %0, %1" : "=v"(r) : "v"(x)); return r; }

#define LOG2E 1.4426950408889634f
#define LN2   0.6931471805599453f

__device__ __forceinline__ float fast_tanh(float x){
  // tanh(x) = 1 - 2/(exp(2x)+1); saturates correctly via inf/0
  float e = fexp2(x * (2.0f*LOG2E));
  return 1.0f - 2.0f*frcp(e + 1.0f);
}
__device__ __forceinline__ float softplus10(float x){
  float e = fexp2(x * (10.0f*LOG2E));
  return (0.1f*LN2) * flog2(1.0f + e);
}

// Record layout (161 used, padded to 164):
//   [0..4]    W0 (softplus10 w_first)
//   [5..9]    bs layer0
//   [10..14]  ta layer0 (tanh a_all)
//   mid layer l=0..3 at base 15+l*35:
//     [base+ j*5+k] = softplus10(w_mid[l][d][n][k][j])   (transposed)
//     [base+25 + j] = bs[l+1]
//     [base+30 + j] = ta[l+1]
//   [155..159] Wl (softplus10 w_last)
//   [160]      b_last
__global__ __launch_bounds__(256) void tennet_prep(
    const float* __restrict__ w_first, const float* __restrict__ w_mid,
    const float* __restrict__ w_last, const float* __restrict__ bs,
    const float* __restrict__ b_last, const float* __restrict__ a_all,
    float* __restrict__ rec)
{
  int rid = blockIdx.x*4 + (threadIdx.x >> 6);   // one wave per (d,n) record
  int lane = threadIdx.x & 63;
  int d = rid / N_;
  int n = rid - d*N_;
  float* dst = rec + rid*REC;
  for (int i = lane; i < 161; i += 64) {
    float v;
    if (i < 5)        v = softplus10(w_first[(d*N_+n)*5 + i]);
    else if (i < 10)  v = bs[(d*N_+n)*5 + (i-5)];                    // l=0
    else if (i < 15)  v = fast_tanh(a_all[(d*N_+n)*5 + (i-10)]);     // l=0
    else if (i < 155) {
      int q = i - 15; int l = q/35; int r2 = q - l*35;
      if (r2 < 25) {
        int j = r2/5, k = r2 - (r2/5)*5;
        v = softplus10(w_mid[((l*D_+d)*N_+n)*25 + k*5 + j]);
      } else if (r2 < 30) {
        v = bs[(((l+1)*D_+d)*N_+n)*5 + (r2-25)];
      } else {
        v = fast_tanh(a_all[(((l+1)*D_+d)*N_+n)*5 + (r2-30)]);
      }
    }
    else if (i < 160) v = softplus10(w_last[(d*N_+n)*5 + (i-155)]);
    else              v = b_last[d*N_+n];
    dst[i] = v;
  }
}

// One wave per (d,n): 64 lanes = 64 consecutive m. Weights are wave-uniform
// -> scalar loads (s_load), matvec = v_fma with SGPR operand. Block = 16 waves
// covering 16 consecutive n and one 64-m chunk; LDS transpose for 64B stores.
__global__ __launch_bounds__(1024) void tennet_main(
    const float* __restrict__ X, const float* __restrict__ rec,
    float* __restrict__ out0)
{
  __shared__ float tr[64*17];
  int bid = blockIdx.x;
  int mb  = bid & 15;          // 16 m-chunks of 64
  int nch = (bid >> 4) & 31;   // 32 n-chunks of 16
  int d   = bid >> 9;          // 10
  int n0 = nch*16;
  int t = threadIdx.x;
  int w = __builtin_amdgcn_readfirstlane(t >> 6);   // wave id, provably uniform
  int lane = t & 63;
  int n = n0 + w;
  int nr = (n < N_) ? n : (N_-1);                   // clamp: compute dup, store masked
  const float* r = rec + (d*N_ + nr)*REC;           // wave-uniform pointer
  int m = mb*64 + lane;
  float x = X[m*D_ + d];

  float phis[5], phid[5];
  // layer 0 (k-dim = 1)
  #pragma unroll
  for (int j = 0; j < 5; ++j) {
    float w0 = r[j];
    float pre = x*w0 + r[5+j];
    float th = fast_tanh(pre);
    float ta = r[10+j];
    phid[j] = w0*(1.0f + ta*(1.0f - th*th));
    phis[j] = pre + th*ta;
  }
  // mid layers
  #pragma unroll
  for (int l = 0; l < 4; ++l) {
    const float* rb = r + 15 + l*35;
    float nphis[5], nphid[5];
    #pragma unroll
    for (int j = 0; j < 5; ++j) {
      float pre = rb[25+j];
      float pd = 0.0f;
      #pragma unroll
      for (int k = 0; k < 5; ++k) {
        float wv = rb[j*5+k];
        pre += phis[k]*wv;
        pd  += phid[k]*wv;
      }
      float th = fast_tanh(pre);
      float ta = rb[30+j];
      nphid[j] = pd*(1.0f + ta*(1.0f - th*th));
      nphis[j] = pre + th*ta;
    }
    #pragma unroll
    for (int j = 0; j < 5; ++j){ phis[j]=nphis[j]; phid[j]=nphid[j]; }
  }
  // last layer + sigmoid'
  float pre = r[160], pd = 0.0f;
  #pragma unroll
  for (int k = 0; k < 5; ++k){ float wv = r[155+k]; pre += phis[k]*wv; pd += phid[k]*wv; }
  float sg = frcp(1.0f + fexp2(-pre*LOG2E));
  float res = pd*sg*(1.0f-sg);

  // transpose 64m x 16n through LDS (stride 17 -> <=2-way banks, free)
  tr[lane*17 + w] = res;
  __syncthreads();
  int tm = t >> 4, tn = t & 15;
  if (n0 + tn < N_)
    out0[((mb*64 + tm)*D_ + d)*N_ + n0 + tn] = tr[tm*17 + tn];
}

// fm[m] = min_n mean_d( -ln(phidot[m,d,n] + 1e-10) )
__global__ __launch_bounds__(512) void tennet_fm(
    const float* __restrict__ out0, float* __restrict__ fm)
{
  int m = blockIdx.x;
  int t = threadIdx.x;
  float val = INFINITY;
  if (t < N_) {
    float acc = 0.0f;
    #pragma unroll
    for (int d = 0; d < D_; ++d) {
      float v = out0[(m*D_ + d)*N_ + t];
      acc += flog2(v + 1e-10f);
    }
    val = -acc * (LN2 / (float)D_);
  }
  #pragma unroll
  for (int off = 32; off; off >>= 1) {
    float o = __shfl_down(val, off, 64);
    val = fminf(val, o);
  }
  __shared__ float red[8];
  int wid = t >> 6;
  if ((t & 63) == 0) red[wid] = val;
  __syncthreads();
  if (t == 0) {
    float v = red[0];
    #pragma unroll
    for (int ww = 1; ww < 8; ++ww) v = fminf(v, red[ww]);
    fm[m] = v;
  }
}

extern "C" void kernel_launch(void* const* d_in, const int* in_sizes, int n_in,
                              void* d_out, int out_size, void* d_ws, size_t ws_size,
                              hipStream_t stream) {
  const float* X       = (const float*)d_in[0];
  const float* w_first = (const float*)d_in[1];
  const float* w_mid   = (const float*)d_in[2];
  const float* w_last  = (const float*)d_in[3];
  const float* bs      = (const float*)d_in[4];
  const float* b_last  = (const float*)d_in[5];
  const float* a_all   = (const float*)d_in[6];
  float* out0 = (float*)d_out;
  float* fm   = out0 + 1024*D_*N_;
  float* rec  = (float*)d_ws;   // 10*500*164*4 = 3.28 MB

  tennet_prep<<<(D_*N_)/4, 256, 0, stream>>>(w_first, w_mid, w_last, bs, b_last, a_all, rec);
  tennet_main<<<10*32*16, 1024, 0, stream>>>(X, rec, out0);
  tennet_fm<<<1024, 512, 0, stream>>>(out0, fm);
}

// Round 3
// 66.472 us; speedup vs baseline: 6.3965x; 1.3661x over previous
//
#include <hip/hip_runtime.h>
#include <math.h>

#define D_ 10
#define N_ 500
#define REC 164   // packed per-(d,n) weight record, floats (even stride -> 8B-aligned pairs)

typedef float f32x2 __attribute__((ext_vector_type(2)));

__device__ __forceinline__ float fexp2(float x){ float r; asm("v_exp_f32 %0, %1" : "=v"(r) : "v"(x)); return r; }
__device__ __forceinline__ float flog2(float x){ float r; asm("v_log_f32 %0, %1" : "=v"(r) : "v"(x)); return r; }
__device__ __forceinline__ float frcp (float x){ float r; asm("v_rcp_f32 %0, %1" : "=v"(r) : "v"(x)); return r; }

#define LOG2E 1.4426950408889634f
#define LN2   0.6931471805599453f

__device__ __forceinline__ float fast_tanh(float x){
  float e = fexp2(x * (2.0f*LOG2E));
  return 1.0f - 2.0f*frcp(e + 1.0f);
}
__device__ __forceinline__ float softplus10(float x){
  float e = fexp2(x * (10.0f*LOG2E));
  return (0.1f*LN2) * flog2(1.0f + e);
}

// ---- packed-f32 primitives (VOP3P). "s" operand = wave-uniform weight pair;
// op_sel/op_sel_hi broadcast word0 (lo) or word1 (hi) to both result halves.
__device__ __forceinline__ f32x2 pk_fma_blo(f32x2 a, f32x2 w, f32x2 c){
  f32x2 d; asm("v_pk_fma_f32 %0, %1, %2, %3 op_sel:[0,0,0] op_sel_hi:[1,0,1]"
               : "=v"(d) : "v"(a), "s"(w), "v"(c)); return d; }
__device__ __forceinline__ f32x2 pk_fma_bhi(f32x2 a, f32x2 w, f32x2 c){
  f32x2 d; asm("v_pk_fma_f32 %0, %1, %2, %3 op_sel:[0,1,0] op_sel_hi:[1,1,1]"
               : "=v"(d) : "v"(a), "s"(w), "v"(c)); return d; }
__device__ __forceinline__ f32x2 pk_mul_blo(f32x2 a, f32x2 w){
  f32x2 d; asm("v_pk_mul_f32 %0, %1, %2 op_sel:[0,0] op_sel_hi:[1,0]"
               : "=v"(d) : "v"(a), "s"(w)); return d; }
__device__ __forceinline__ f32x2 pk_mul_bhi(f32x2 a, f32x2 w){
  f32x2 d; asm("v_pk_mul_f32 %0, %1, %2 op_sel:[0,1] op_sel_hi:[1,1]"
               : "=v"(d) : "v"(a), "s"(w)); return d; }
__device__ __forceinline__ f32x2 pk_mul(f32x2 a, f32x2 b){
  f32x2 d; asm("v_pk_mul_f32 %0, %1, %2" : "=v"(d) : "v"(a), "v"(b)); return d; }
__device__ __forceinline__ f32x2 pk_add(f32x2 a, f32x2 b){
  f32x2 d; asm("v_pk_add_f32 %0, %1, %2" : "=v"(d) : "v"(a), "v"(b)); return d; }
__device__ __forceinline__ f32x2 pk_nfma(f32x2 a, f32x2 b, f32x2 c){ // c - a*b
  f32x2 d; asm("v_pk_fma_f32 %0, %1, %2, %3 neg_lo:[1,0,0] neg_hi:[1,0,0]"
               : "=v"(d) : "v"(a), "v"(b), "v"(c)); return d; }

// off is a compile-time constant after unroll; parity picks the broadcast word.
#define LD2(off)        (*(const f32x2*)(r + ((off) & ~1)))
#define FMA_B(a, off, c) (((off)&1) ? pk_fma_bhi((a), LD2(off), (c)) : pk_fma_blo((a), LD2(off), (c)))
#define MUL_B(a, off)    (((off)&1) ? pk_mul_bhi((a), LD2(off))      : pk_mul_blo((a), LD2(off)))

// Record layout (161 used, padded to 164):
//   [0..4] W0   [5..9] bs0   [10..14] ta0
//   mid l=0..3 at base 15+l*35: [base+j*5+k]=W^T, [base+25+j]=bs, [base+30+j]=ta
//   [155..159] Wl   [160] b_last
__global__ __launch_bounds__(256) void tennet_prep(
    const float* __restrict__ w_first, const float* __restrict__ w_mid,
    const float* __restrict__ w_last, const float* __restrict__ bs,
    const float* __restrict__ b_last, const float* __restrict__ a_all,
    float* __restrict__ rec)
{
  int rid = blockIdx.x*4 + (threadIdx.x >> 6);
  int lane = threadIdx.x & 63;
  int d = rid / N_;
  int n = rid - d*N_;
  float* dst = rec + rid*REC;
  for (int i = lane; i < 161; i += 64) {
    float v;
    if (i < 5)        v = softplus10(w_first[(d*N_+n)*5 + i]);
    else if (i < 10)  v = bs[(d*N_+n)*5 + (i-5)];
    else if (i < 15)  v = fast_tanh(a_all[(d*N_+n)*5 + (i-10)]);
    else if (i < 155) {
      int q = i - 15; int l = q/35; int r2 = q - l*35;
      if (r2 < 25) {
        int j = r2/5, k = r2 - (r2/5)*5;
        v = softplus10(w_mid[((l*D_+d)*N_+n)*25 + k*5 + j]);
      } else if (r2 < 30) {
        v = bs[(((l+1)*D_+d)*N_+n)*5 + (r2-25)];
      } else {
        v = fast_tanh(a_all[(((l+1)*D_+d)*N_+n)*5 + (r2-30)]);
      }
    }
    else if (i < 160) v = softplus10(w_last[(d*N_+n)*5 + (i-155)]);
    else              v = b_last[d*N_+n];
    dst[i] = v;
  }
}

// One wave per (d,n); 64 lanes x 2 m per thread (m and m+64), packed f32 math.
__global__ __launch_bounds__(1024) void tennet_main(
    const float* __restrict__ X, const float* __restrict__ rec,
    float* __restrict__ out0)
{
  __shared__ float tr[128*17];
  int bid = blockIdx.x;
  int mb  = bid & 7;           // 8 chunks of 128 m
  int nch = (bid >> 3) & 31;   // 32 chunks of 16 n
  int d   = bid >> 8;          // 10
  int n0 = nch*16;
  int t = threadIdx.x;
  int wv = __builtin_amdgcn_readfirstlane(t >> 6);
  int lane = t & 63;
  int n = n0 + wv;
  int nr = (n < N_) ? n : (N_-1);
  const float* r = rec + (d*N_ + nr)*REC;   // wave-uniform -> s_load
  int m0 = mb*128 + lane;

  f32x2 x;
  x.x = X[m0*D_ + d];
  x.y = X[(m0+64)*D_ + d];

  const f32x2 ONE = {1.0f, 1.0f};
  const f32x2 TWO = {2.0f, 2.0f};
  const f32x2 K2  = {2.0f*LOG2E, 2.0f*LOG2E};
  const f32x2 NL2E = {-LOG2E, -LOG2E};

  f32x2 phis[5], phid[5];
  // layer 0
  #pragma unroll
  for (int j = 0; j < 5; ++j) {
    f32x2 pre = FMA_B(x, j, MUL_B(ONE, 5+j));     // x*w0 + b
    f32x2 tt = pk_mul(pre, K2);
    f32x2 e; e.x = fexp2(tt.x); e.y = fexp2(tt.y);
    f32x2 p1 = pk_add(e, ONE);
    f32x2 rc; rc.x = frcp(p1.x); rc.y = frcp(p1.y);
    f32x2 th = pk_nfma(TWO, rc, ONE);             // tanh
    f32x2 td = pk_nfma(th, th, ONE);              // 1 - th^2
    f32x2 u  = FMA_B(td, 10+j, ONE);              // 1 + ta*td
    phid[j] = MUL_B(u, j);                        // w0 * u
    phis[j] = FMA_B(th, 10+j, pre);               // pre + th*ta
  }
  // mid layers
  #pragma unroll
  for (int l = 0; l < 4; ++l) {
    const int base = 15 + l*35;
    f32x2 nphis[5], nphid[5];
    #pragma unroll
    for (int j = 0; j < 5; ++j) {
      f32x2 pre = FMA_B(phis[0], base + j*5, MUL_B(ONE, base + 25 + j));
      f32x2 pd  = MUL_B(phid[0], base + j*5);
      #pragma unroll
      for (int k = 1; k < 5; ++k) {
        pre = FMA_B(phis[k], base + j*5 + k, pre);
        pd  = FMA_B(phid[k], base + j*5 + k, pd);
      }
      f32x2 tt = pk_mul(pre, K2);
      f32x2 e; e.x = fexp2(tt.x); e.y = fexp2(tt.y);
      f32x2 p1 = pk_add(e, ONE);
      f32x2 rc; rc.x = frcp(p1.x); rc.y = frcp(p1.y);
      f32x2 th = pk_nfma(TWO, rc, ONE);
      f32x2 td = pk_nfma(th, th, ONE);
      f32x2 u  = FMA_B(td, base + 30 + j, ONE);
      nphid[j] = pk_mul(pd, u);
      nphis[j] = FMA_B(th, base + 30 + j, pre);
    }
    #pragma unroll
    for (int j = 0; j < 5; ++j){ phis[j]=nphis[j]; phid[j]=nphid[j]; }
  }
  // last layer + sigmoid'
  f32x2 pre = FMA_B(phis[0], 155, MUL_B(ONE, 160));
  f32x2 pd  = MUL_B(phid[0], 155);
  #pragma unroll
  for (int k = 1; k < 5; ++k) {
    pre = FMA_B(phis[k], 155 + k, pre);
    pd  = FMA_B(phid[k], 155 + k, pd);
  }
  f32x2 tt = pk_mul(pre, NL2E);
  f32x2 e; e.x = fexp2(tt.x); e.y = fexp2(tt.y);
  f32x2 p1 = pk_add(e, ONE);
  f32x2 sg; sg.x = frcp(p1.x); sg.y = frcp(p1.y);
  f32x2 om = pk_nfma(sg, ONE, ONE);               // 1 - sg
  f32x2 res = pk_mul(pk_mul(pd, sg), om);

  // transpose 128m x 16n through LDS (stride 17: odd -> 2-way banks, free)
  tr[lane*17 + wv] = res.x;
  tr[(lane+64)*17 + wv] = res.y;
  __syncthreads();
  int tn = t & 15;
  #pragma unroll
  for (int rr = (t >> 4); rr < 128; rr += 64) {
    if (n0 + tn < N_)
      out0[((mb*128 + rr)*D_ + d)*N_ + n0 + tn] = tr[rr*17 + tn];
  }
}

// fm[m] = min_n mean_d( -ln(phidot[m,d,n] + 1e-10) )
__global__ __launch_bounds__(512) void tennet_fm(
    const float* __restrict__ out0, float* __restrict__ fm)
{
  int m = blockIdx.x;
  int t = threadIdx.x;
  float val = INFINITY;
  if (t < N_) {
    float acc = 0.0f;
    #pragma unroll
    for (int d = 0; d < D_; ++d) {
      float v = out0[(m*D_ + d)*N_ + t];
      acc += flog2(v + 1e-10f);
    }
    val = -acc * (LN2 / (float)D_);
  }
  #pragma unroll
  for (int off = 32; off; off >>= 1) {
    float o = __shfl_down(val, off, 64);
    val = fminf(val, o);
  }
  __shared__ float red[8];
  int wid = t >> 6;
  if ((t & 63) == 0) red[wid] = val;
  __syncthreads();
  if (t == 0) {
    float v = red[0];
    #pragma unroll
    for (int ww = 1; ww < 8; ++ww) v = fminf(v, red[ww]);
    fm[m] = v;
  }
}

extern "C" void kernel_launch(void* const* d_in, const int* in_sizes, int n_in,
                              void* d_out, int out_size, void* d_ws, size_t ws_size,
                              hipStream_t stream) {
  const float* X       = (const float*)d_in[0];
  const float* w_first = (const float*)d_in[1];
  const float* w_mid   = (const float*)d_in[2];
  const float* w_last  = (const float*)d_in[3];
  const float* bs      = (const float*)d_in[4];
  const float* b_last  = (const float*)d_in[5];
  const float* a_all   = (const float*)d_in[6];
  float* out0 = (float*)d_out;
  float* fm   = out0 + 1024*D_*N_;
  float* rec  = (float*)d_ws;   // 10*500*164*4 = 3.28 MB

  tennet_prep<<<(D_*N_)/4, 256, 0, stream>>>(w_first, w_mid, w_last, bs, b_last, a_all, rec);
  tennet_main<<<10*32*8, 1024, 0, stream>>>(X, rec, out0);
  tennet_fm<<<1024, 512, 0, stream>>>(out0, fm);
}